// Round 10
// baseline (798.858 us; speedup 1.0000x reference)
//
#include <hip/hip_runtime.h>

#define NPTS 16384
#define CDIM 64

using bf16x8 = __attribute__((ext_vector_type(8))) short;
using f32x4  = __attribute__((ext_vector_type(4))) float;

static __device__ __forceinline__ float b2f(short h){
  unsigned u = ((unsigned)(unsigned short)h) << 16;
  return __builtin_bit_cast(float, u);
}
static __device__ __forceinline__ short f2b(float f){
  unsigned u = __builtin_bit_cast(unsigned, f);
  u = (u + 0x7fffu + ((u >> 16) & 1u)) >> 16;
  return (short)u;
}

// One kernel, 512 threads, 81920 B LDS (round-2-proven shape).
// Inputs fp32; OUTPUT fp32 (root-cause fix: previous rounds stored bf16
// shorts into a float* buffer -> half-filled buffer -> absmax = max|ref|).
// Phase 1: 2-term bf16 split distance GEMM (hh+hm+mh), per-half top-16.
// Phase 2: exact fp32 rescore of the 32 candidates + bitonic top-16 + MLP.
// LDS: P1 As@0 Am@9216 Bs0@18432 Bm0@27648 Bs1@36864 Bm1@46080 sqs@55296
//      P2 Wt@0(65536) cidx@65536(8192)
__global__ __launch_bounds__(512) void k_fused(const float* __restrict__ xf,
    const float* __restrict__ Wf, const float* __restrict__ bf,
    float* __restrict__ y){
  __shared__ __align__(16) char smem[81920];
  short* As  = (short*)smem;
  short* Am  = (short*)(smem + 9216);
  float* sqs = (float*)(smem + 55296);    // 2 x 64, pre-scaled by 0.5
  short* Wt  = (short*)smem;              // phase 2
  int*  cidx = (int*)(smem + 65536);      // 64 x 32

  const int tid = threadIdx.x;
  const int lane = tid & 63, w = tid >> 6;
  const int l15 = lane & 15, quad = lane >> 4;
  const int h = w >> 2, sw = w & 3;       // j-half, i-subtile
  const int ht = tid & 255;               // id within half-group
  const int i0 = blockIdx.x * 64;
  const int rb = i0 + sw*16;

  // ---- stage A tile (64x64), 2-term bf16 split, stride 72 ----
  {
    int row = tid >> 3, seg = tid & 7;
    const float* p = xf + (i0+row)*CDIM + seg*8;
    bf16x8 vh, vm;
    #pragma unroll
    for (int e = 0; e < 8; ++e){
      float v = p[e];
      short a = f2b(v); float r1 = v - b2f(a);
      vh[e] = a; vm[e] = f2b(r1);
    }
    *(bf16x8*)(As + row*72 + seg*8) = vh;
    *(bf16x8*)(Am + row*72 + seg*8) = vm;
  }

  short* Bs_h = (short*)(smem + 18432 + h*18432);
  short* Bm_h = Bs_h + 4608;
  float* sq_h = sqs + h*64;

  float lv[4]; int li[4]; float thr[4];
  #pragma unroll
  for (int r = 0; r < 4; ++r){
    lv[r] = __builtin_inff(); li[r] = 0; thr[r] = __builtin_inff();
  }

  // ---- phase 1: split distance GEMM + streaming top-16 per half ----
  #pragma unroll 1
  for (int t = 0; t < 128; ++t){
    const int j0 = h*8192 + t*64;
    __syncthreads();                    // covers A at t=0; B-reuse after
    #pragma unroll
    for (int it = 0; it < 2; ++it){
      int row = it*32 + (ht >> 3), seg = ht & 7;
      const float* p = xf + (j0+row)*CDIM + seg*8;
      bf16x8 vh, vm;
      float ps = 0.f;
      #pragma unroll
      for (int e = 0; e < 8; ++e){
        float f = p[e];
        short a = f2b(f); float r1 = f - b2f(a);
        vh[e] = a; vm[e] = f2b(r1);
        ps = fmaf(f, f, ps);
      }
      *(bf16x8*)(Bs_h + row*72 + seg*8) = vh;
      *(bf16x8*)(Bm_h + row*72 + seg*8) = vm;
      ps += __shfl_down(ps, 4);
      ps += __shfl_down(ps, 2);
      ps += __shfl_down(ps, 1);
      if (seg == 0) sq_h[row] = 0.5f * ps;
    }
    __syncthreads();

    f32x4 acc[4], accS[4];
    #pragma unroll
    for (int js = 0; js < 4; ++js){
      acc[js]  = (f32x4){0.f,0.f,0.f,0.f};
      accS[js] = (f32x4){0.f,0.f,0.f,0.f};
    }
    #pragma unroll
    for (int ks = 0; ks < 2; ++ks){
      bf16x8 ah = *(const bf16x8*)(As + (sw*16 + l15)*72 + quad*8 + ks*32);
      bf16x8 am = *(const bf16x8*)(Am + (sw*16 + l15)*72 + quad*8 + ks*32);
      #pragma unroll
      for (int js = 0; js < 4; ++js){
        bf16x8 bh = *(const bf16x8*)(Bs_h + (js*16 + l15)*72 + quad*8 + ks*32);
        bf16x8 bm = *(const bf16x8*)(Bm_h + (js*16 + l15)*72 + quad*8 + ks*32);
        acc[js]  = __builtin_amdgcn_mfma_f32_16x16x32_bf16(ah, bh, acc[js],  0,0,0);
        accS[js] = __builtin_amdgcn_mfma_f32_16x16x32_bf16(ah, bm, accS[js], 0,0,0);
        accS[js] = __builtin_amdgcn_mfma_f32_16x16x32_bf16(am, bh, accS[js], 0,0,0);
      }
    }

    // rank by s = 0.5*sq[j] - dot  (monotone in d = 2s + sq[i])
    const bool maydiag = (j0 < rb + 16) && (rb < j0 + 64);
    #pragma unroll
    for (int js = 0; js < 4; ++js){
      float sqv = sq_h[js*16 + l15];
      float s4[4];
      #pragma unroll
      for (int r = 0; r < 4; ++r) s4[r] = sqv - (acc[js][r] + accS[js][r]);
      if (maydiag){
        int jg = j0 + js*16 + l15;
        #pragma unroll
        for (int r = 0; r < 4; ++r)
          if (jg == rb + quad*4 + r) s4[r] = __builtin_inff();
      }
      bool hit = (s4[0] < thr[0]) || (s4[1] < thr[1]) ||
                 (s4[2] < thr[2]) || (s4[3] < thr[3]);
      if (__any(hit)){
        #pragma unroll
        for (int r = 0; r < 4; ++r){
          unsigned long long bal = __ballot(s4[r] < thr[r]);
          unsigned qb = (unsigned)((bal >> (quad*16)) & 0xffffull);
          while (qb){
            int jj = __builtin_ctz(qb); qb &= qb - 1u;
            float cv = __shfl(s4[r], quad*16 + jj);
            int   cj = j0 + js*16 + jj;
            unsigned long long b2 = __ballot(lv[r] <= cv);
            int pos = __popc((unsigned)((b2 >> (quad*16)) & 0xffffull));
            float upv = __shfl_up(lv[r], 1, 16);
            int   upi = __shfl_up(li[r], 1, 16);
            if (l15 == pos){ lv[r] = cv; li[r] = cj; }
            else if (l15 > pos){ lv[r] = upv; li[r] = upi; }
            thr[r] = __shfl(lv[r], (lane & 48) | 15);
          }
        }
      }
    }
  }

  __syncthreads();                       // phase-1 LDS dead from here
  #pragma unroll
  for (int r = 0; r < 4; ++r){
    int rl = sw*16 + quad*4 + r;
    cidx[rl*32 + h*16 + l15] = li[r];
  }

  // ---- stage W^T as bf16 (XOR-swizzled 16B chunks): Wt[n][k]=W[k][n] ----
  {
    int n = tid & 255, kb = (tid >> 8) * 64;
    #pragma unroll 1
    for (int kk = 0; kk < 64; ++kk){
      int k = kb + kk;
      int chunk = (k >> 3) ^ (n & 15);
      Wt[n*128 + chunk*8 + (k & 7)] = f2b(Wf[k*256 + n]);
    }
  }
  __syncthreads();

  // ---- phase 2: exact fp32 rescore + bitonic top-16 + MLP + store ----
  #pragma unroll 1
  for (int it = 0; it < 8; ++it){
    const int rl = w*8 + it;
    const int i  = i0 + rl;
    const int sl = lane & 31;
    int idx = cidx[rl*32 + sl] & (NPTS - 1);

    // exact rescore: d = fl(sq_i + sq_j) - 2*dot, numpy-style pairwise sums
    float v;
    {
      const float* pi2 = xf + i*CDIM;
      const float* pj2 = xf + idx*CDIM;
      float qa[8], qb[8], qd[8];
      #pragma unroll
      for (int e = 0; e < 8; ++e){
        float a = pi2[e], b = pj2[e];
        qa[e] = a*a; qb[e] = b*b; qd[e] = a*b;
      }
      #pragma unroll
      for (int k2 = 1; k2 < 8; ++k2)
        #pragma unroll
        for (int e = 0; e < 8; ++e){
          float a = pi2[k2*8+e], b = pj2[k2*8+e];
          qa[e] += a*a; qb[e] += b*b; qd[e] += a*b;
        }
      float sa = ((qa[0]+qa[1])+(qa[2]+qa[3])) + ((qa[4]+qa[5])+(qa[6]+qa[7]));
      float sb = ((qb[0]+qb[1])+(qb[2]+qb[3])) + ((qb[4]+qb[5])+(qb[6]+qb[7]));
      float sd = ((qd[0]+qd[1])+(qd[2]+qd[3])) + ((qd[4]+qd[5])+(qd[6]+qd[7]));
      v = fmaf(-2.f, sd, sa + sb);
      if (idx == i) v = __builtin_inff();
    }

    // bitonic sort 32 by (v, idx) ascending (lanes 32-63 duplicate)
    #pragma unroll
    for (int k = 2; k <= 32; k <<= 1){
      #pragma unroll
      for (int j = k >> 1; j > 0; j >>= 1){
        float pv = __shfl_xor(v, j); int pi = __shfl_xor(idx, j);
        bool dir = ((sl & k) == 0);
        bool lower = ((sl & j) == 0);
        bool pless = (pv < v) || (pv == v && pi < idx);
        bool take = (lower == dir) ? pless : !pless;
        if (take){ v = pv; idx = pi; }
      }
    }
    int nb = __shfl(idx, l15) & (NPTS - 1);
    const float* xi = xf + i*CDIM;
    const float* xj = xf + nb*CDIM;
    bf16x8 afr[4];
    #pragma unroll
    for (int e = 0; e < 8; ++e){
      float a0 = xi[quad*8 + e];
      float a1 = xi[32 + quad*8 + e];
      float b0 = xj[quad*8 + e];
      float b1 = xj[32 + quad*8 + e];
      afr[0][e] = f2b(a0);
      afr[1][e] = f2b(a1);
      afr[2][e] = f2b(b0 - a0);
      afr[3][e] = f2b(b1 - a1);
    }
    f32x4 acc2[16];
    #pragma unroll
    for (int nt = 0; nt < 16; ++nt) acc2[nt] = (f32x4){0.f,0.f,0.f,0.f};
    #pragma unroll
    for (int ks = 0; ks < 4; ++ks){
      #pragma unroll
      for (int nt = 0; nt < 16; ++nt){
        int chunkS = ((ks*4 + quad) ^ l15);
        bf16x8 b = *(const bf16x8*)(Wt + (nt*16 + l15)*128 + chunkS*8);
        acc2[nt] = __builtin_amdgcn_mfma_f32_16x16x32_bf16(afr[ks], b, acc2[nt], 0, 0, 0);
      }
    }
    #pragma unroll
    for (int nt = 0; nt < 16; ++nt){
      float m = fmaxf(fmaxf(acc2[nt][0], acc2[nt][1]), fmaxf(acc2[nt][2], acc2[nt][3]));
      m = fmaxf(m, __shfl_xor(m, 16));
      m = fmaxf(m, __shfl_xor(m, 32));
      int col = nt*16 + l15;
      float o = fmaxf(m + bf[col], 0.f);
      if (lane < 16)
        y[(i*4 + (col & 3))*CDIM + (col >> 2)] = o;   // fp32 store
    }
  }
}

extern "C" void kernel_launch(void* const* d_in, const int* in_sizes, int n_in,
                              void* d_out, int out_size, void* d_ws, size_t ws_size,
                              hipStream_t stream){
  const float* x    = (const float*)d_in[0];
  const float* Wm   = (const float*)d_in[1];
  const float* bias = (const float*)d_in[2];
  float* y = (float*)d_out;
  (void)d_ws; (void)ws_size; (void)in_sizes; (void)n_in; (void)out_size;
  k_fused<<<NPTS/64, 512, 0, stream>>>(x, Wm, bias, y);
}

// Round 11
// 588.713 us; speedup vs baseline: 1.3570x; 1.3570x over previous
//
#include <hip/hip_runtime.h>

#define NPTS 16384
#define CDIM 64

using bf16x8 = __attribute__((ext_vector_type(8))) short;
using s16x4  = __attribute__((ext_vector_type(4))) short;
using f32x4  = __attribute__((ext_vector_type(4))) float;
using i32x4  = __attribute__((ext_vector_type(4))) int;

static __device__ __forceinline__ float b2f(short h){
  unsigned u = ((unsigned)(unsigned short)h) << 16;
  return __builtin_bit_cast(float, u);
}
static __device__ __forceinline__ short f2b(float f){
  unsigned u = __builtin_bit_cast(unsigned, f);
  u = (u + 0x7fffu + ((u >> 16) & 1u)) >> 16;
  return (short)u;
}

// ---- K1: split x into hi/mid bf16 planes + 0.5*||x||^2 ----
// 256 blocks x 256 thr; thread = (row, quarter-of-row 16 floats)
__global__ __launch_bounds__(256) void k_prep(const float* __restrict__ xf,
    short* __restrict__ xh, short* __restrict__ xm, float* __restrict__ sq05){
  const int tid = threadIdx.x;
  const int row = blockIdx.x*64 + (tid >> 2);
  const int part = tid & 3;
  const float* p = xf + row*CDIM + part*16;
  float ps = 0.f;
  bf16x8 vh0, vm0, vh1, vm1;
  #pragma unroll
  for (int e = 0; e < 8; ++e){
    float f = p[e];
    short a = f2b(f); float r = f - b2f(a);
    vh0[e] = a; vm0[e] = f2b(r);
    ps = fmaf(f, f, ps);
  }
  #pragma unroll
  for (int e = 0; e < 8; ++e){
    float f = p[8 + e];
    short a = f2b(f); float r = f - b2f(a);
    vh1[e] = a; vm1[e] = f2b(r);
    ps = fmaf(f, f, ps);
  }
  *(bf16x8*)(xh + row*CDIM + part*16)     = vh0;
  *(bf16x8*)(xh + row*CDIM + part*16 + 8) = vh1;
  *(bf16x8*)(xm + row*CDIM + part*16)     = vm0;
  *(bf16x8*)(xm + row*CDIM + part*16 + 8) = vm1;
  ps += __shfl_down(ps, 2);
  ps += __shfl_down(ps, 1);
  if (part == 0) sq05[row] = 0.5f * ps;
}

// ---- K2: W^T bf16, XOR-swizzled (same layout k_mlp reads) ----
// 32 blocks x 256 thr: block = 4 consecutive k, thread = n
__global__ __launch_bounds__(256) void k_wprep(const float* __restrict__ Wf,
    short* __restrict__ WtG){
  const int n = threadIdx.x;
  const int kq = blockIdx.x;               // 0..31 -> k = kq*4+e
  const int chunk = (kq >> 1) ^ (n & 15);  // (k>>3) constant over e
  s16x4 v;
  #pragma unroll
  for (int e = 0; e < 4; ++e) v[e] = f2b(Wf[(kq*4 + e)*256 + n]);
  *(s16x4*)(WtG + n*128 + chunk*8 + (kq & 1)*4) = v;
}

// ---- K3: distance GEMM (hh+hm+mh) + streaming top-16 per j-quarter ----
// grid 1024 = (i-tile 0..255) x (j-quarter 0..3); 256 thr = 4 waves.
// Wave w owns i-rows rb..rb+15; A-frags in regs; B double-buffered LDS.
__global__ __launch_bounds__(256) void k_knn(const short* __restrict__ xh,
    const short* __restrict__ xm, const float* __restrict__ sq05,
    int* __restrict__ cand){
  __shared__ __align__(16) short Bh[2][64*72];
  __shared__ __align__(16) short Bm[2][64*72];
  const int tid = threadIdx.x, lane = tid & 63, w = tid >> 6;
  const int l15 = lane & 15, quad = lane >> 4;
  const int q = blockIdx.x & 3, ib = blockIdx.x >> 2;
  const int rb = ib*64 + w*16;
  const int jbase = q*4096;

  bf16x8 ah[2], am[2];
  #pragma unroll
  for (int ks = 0; ks < 2; ++ks){
    ah[ks] = *(const bf16x8*)(xh + (rb + l15)*CDIM + ks*32 + quad*8);
    am[ks] = *(const bf16x8*)(xm + (rb + l15)*CDIM + ks*32 + quad*8);
  }

  float lv[4]; int li[4]; float thr[4];
  #pragma unroll
  for (int r = 0; r < 4; ++r){
    lv[r] = __builtin_inff(); li[r] = 0; thr[r] = __builtin_inff();
  }

  // stage tile 0
  #pragma unroll
  for (int g = 0; g < 2; ++g){
    int c = g*256 + tid, row = c >> 3, seg = c & 7;
    int off = row*72 + seg*8;
    *(bf16x8*)(&Bh[0][off]) = *(const bf16x8*)(xh + (jbase + row)*CDIM + seg*8);
    *(bf16x8*)(&Bm[0][off]) = *(const bf16x8*)(xm + (jbase + row)*CDIM + seg*8);
  }
  __syncthreads();

  #pragma unroll 1
  for (int t = 0; t < 64; ++t){
    const int cur = t & 1;
    const int j0 = jbase + t*64;
    if (t < 63){
      const int jn = j0 + 64;
      #pragma unroll
      for (int g = 0; g < 2; ++g){
        int c = g*256 + tid, row = c >> 3, seg = c & 7;
        int off = row*72 + seg*8;
        *(bf16x8*)(&Bh[cur^1][off]) = *(const bf16x8*)(xh + (jn + row)*CDIM + seg*8);
        *(bf16x8*)(&Bm[cur^1][off]) = *(const bf16x8*)(xm + (jn + row)*CDIM + seg*8);
      }
    }

    f32x4 acc[4], accS[4];
    #pragma unroll
    for (int js = 0; js < 4; ++js){
      acc[js]  = (f32x4){0.f,0.f,0.f,0.f};
      accS[js] = (f32x4){0.f,0.f,0.f,0.f};
    }
    #pragma unroll
    for (int ks = 0; ks < 2; ++ks){
      #pragma unroll
      for (int js = 0; js < 4; ++js){
        int off = (js*16 + l15)*72 + (ks*4 + quad)*8;
        bf16x8 bh = *(const bf16x8*)(&Bh[cur][off]);
        bf16x8 bm = *(const bf16x8*)(&Bm[cur][off]);
        acc[js]  = __builtin_amdgcn_mfma_f32_16x16x32_bf16(ah[ks], bh, acc[js],  0,0,0);
        accS[js] = __builtin_amdgcn_mfma_f32_16x16x32_bf16(ah[ks], bm, accS[js], 0,0,0);
        accS[js] = __builtin_amdgcn_mfma_f32_16x16x32_bf16(am[ks], bh, accS[js], 0,0,0);
      }
    }

    // rank by s = 0.5*sq[j] - dot (monotone in d)
    const bool maydiag = (j0 < rb + 16) && (rb < j0 + 64);
    #pragma unroll
    for (int js = 0; js < 4; ++js){
      float sqv = sq05[j0 + js*16 + l15];
      float s4[4];
      #pragma unroll
      for (int r = 0; r < 4; ++r) s4[r] = sqv - (acc[js][r] + accS[js][r]);
      if (maydiag){
        int jg = j0 + js*16 + l15;
        #pragma unroll
        for (int r = 0; r < 4; ++r)
          if (jg == rb + quad*4 + r) s4[r] = __builtin_inff();
      }
      bool hit = (s4[0] < thr[0]) || (s4[1] < thr[1]) ||
                 (s4[2] < thr[2]) || (s4[3] < thr[3]);
      if (__any(hit)){
        #pragma unroll
        for (int r = 0; r < 4; ++r){
          unsigned long long bal = __ballot(s4[r] < thr[r]);
          unsigned qb = (unsigned)((bal >> (quad*16)) & 0xffffull);
          while (qb){
            int jj = __builtin_ctz(qb); qb &= qb - 1u;
            float cv = __shfl(s4[r], quad*16 + jj);
            int   cj = j0 + js*16 + jj;
            unsigned long long b2 = __ballot(lv[r] <= cv);
            int pos = __popc((unsigned)((b2 >> (quad*16)) & 0xffffull));
            float upv = __shfl_up(lv[r], 1, 16);
            int   upi = __shfl_up(li[r], 1, 16);
            if (l15 == pos){ lv[r] = cv; li[r] = cj; }
            else if (l15 > pos){ lv[r] = upv; li[r] = upi; }
            thr[r] = __shfl(lv[r], (lane & 48) | 15);
          }
        }
      }
    }
    __syncthreads();
  }

  #pragma unroll
  for (int r = 0; r < 4; ++r)
    cand[(rb + quad*4 + r)*64 + q*16 + l15] = li[r];
}

// ---- K4: exact fp32 rescore of 64 candidates + bitonic top-16 + MLP ----
// grid 512 x 256 thr: block = 32 points, wave = 8 points.
__global__ __launch_bounds__(256) void k_mlp(const float* __restrict__ xf,
    const short* __restrict__ WtG, const float* __restrict__ bfp,
    const int* __restrict__ cand, float* __restrict__ y){
  __shared__ __align__(16) short Wt[256*128];
  const int tid = threadIdx.x, lane = tid & 63, w = tid >> 6;
  const int l15 = lane & 15, quad = lane >> 4;
  for (int c = tid; c < 4096; c += 256)
    ((i32x4*)Wt)[c] = ((const i32x4*)WtG)[c];
  __syncthreads();
  const int ibase = blockIdx.x*32 + w*8;

  #pragma unroll 1
  for (int it = 0; it < 8; ++it){
    const int i = ibase + it;
    int idx = cand[i*64 + lane] & (NPTS - 1);

    // exact rescore: d = fl(sq_i + sq_j) - 2*dot (numpy pairwise sums)
    float v;
    {
      const float* pi2 = xf + i*CDIM;
      const float* pj2 = xf + idx*CDIM;
      float qa[8], qb[8], qd[8];
      #pragma unroll
      for (int e = 0; e < 8; ++e){
        float a = pi2[e], b = pj2[e];
        qa[e] = a*a; qb[e] = b*b; qd[e] = a*b;
      }
      #pragma unroll
      for (int k2 = 1; k2 < 8; ++k2)
        #pragma unroll
        for (int e = 0; e < 8; ++e){
          float a = pi2[k2*8+e], b = pj2[k2*8+e];
          qa[e] += a*a; qb[e] += b*b; qd[e] += a*b;
        }
      float sa = ((qa[0]+qa[1])+(qa[2]+qa[3])) + ((qa[4]+qa[5])+(qa[6]+qa[7]));
      float sb = ((qb[0]+qb[1])+(qb[2]+qb[3])) + ((qb[4]+qb[5])+(qb[6]+qb[7]));
      float sd = ((qd[0]+qd[1])+(qd[2]+qd[3])) + ((qd[4]+qd[5])+(qd[6]+qd[7]));
      v = fmaf(-2.f, sd, sa + sb);
      if (idx == i) v = __builtin_inff();
    }

    // bitonic sort 64 by (v, idx) ascending
    #pragma unroll
    for (int k = 2; k <= 64; k <<= 1){
      #pragma unroll
      for (int j = k >> 1; j > 0; j >>= 1){
        float pv = __shfl_xor(v, j); int pi = __shfl_xor(idx, j);
        bool dir = ((lane & k) == 0);
        bool lower = ((lane & j) == 0);
        bool pless = (pv < v) || (pv == v && pi < idx);
        bool take = (lower == dir) ? pless : !pless;
        if (take){ v = pv; idx = pi; }
      }
    }
    int nb = __shfl(idx, l15) & (NPTS - 1);

    const float* xi = xf + i*CDIM;
    const float* xj = xf + nb*CDIM;
    bf16x8 afr[4];
    #pragma unroll
    for (int e = 0; e < 8; ++e){
      float a0 = xi[quad*8 + e];
      float a1 = xi[32 + quad*8 + e];
      float b0 = xj[quad*8 + e];
      float b1 = xj[32 + quad*8 + e];
      afr[0][e] = f2b(a0);
      afr[1][e] = f2b(a1);
      afr[2][e] = f2b(b0 - a0);
      afr[3][e] = f2b(b1 - a1);
    }
    f32x4 acc2[16];
    #pragma unroll
    for (int nt = 0; nt < 16; ++nt) acc2[nt] = (f32x4){0.f,0.f,0.f,0.f};
    #pragma unroll
    for (int ks = 0; ks < 4; ++ks){
      #pragma unroll
      for (int nt = 0; nt < 16; ++nt){
        int chunkS = ((ks*4 + quad) ^ l15);
        bf16x8 b = *(const bf16x8*)(Wt + (nt*16 + l15)*128 + chunkS*8);
        acc2[nt] = __builtin_amdgcn_mfma_f32_16x16x32_bf16(afr[ks], b, acc2[nt], 0, 0, 0);
      }
    }
    #pragma unroll
    for (int nt = 0; nt < 16; ++nt){
      float m = fmaxf(fmaxf(acc2[nt][0], acc2[nt][1]), fmaxf(acc2[nt][2], acc2[nt][3]));
      m = fmaxf(m, __shfl_xor(m, 16));
      m = fmaxf(m, __shfl_xor(m, 32));
      int col = nt*16 + l15;
      float o = fmaxf(m + bfp[col], 0.f);
      if (lane < 16)
        y[(i*4 + (col & 3))*CDIM + (col >> 2)] = o;
    }
  }
}

extern "C" void kernel_launch(void* const* d_in, const int* in_sizes, int n_in,
                              void* d_out, int out_size, void* d_ws, size_t ws_size,
                              hipStream_t stream){
  const float* x    = (const float*)d_in[0];
  const float* Wm   = (const float*)d_in[1];
  const float* bias = (const float*)d_in[2];
  float* y = (float*)d_out;
  char* ws = (char*)d_ws;
  short* xh   = (short*)ws;                              // 2 MB
  short* xm   = (short*)(ws + (2 << 20));                // 2 MB
  float* sq05 = (float*)(ws + (4 << 20));                // 64 KB
  short* WtG  = (short*)(ws + (4 << 20) + (64 << 10));   // 64 KB
  int*   cand = (int*)  (ws + (4 << 20) + (128 << 10));  // 4 MB
  (void)in_sizes; (void)n_in; (void)out_size; (void)ws_size;

  k_prep <<<256,  256, 0, stream>>>(x, xh, xm, sq05);
  k_wprep<<<32,   256, 0, stream>>>(Wm, WtG);
  k_knn  <<<1024, 256, 0, stream>>>(xh, xm, sq05, cand);
  k_mlp  <<<512,  256, 0, stream>>>(x, WtG, bias, cand, y);
}

// Round 12
// 519.327 us; speedup vs baseline: 1.5383x; 1.1336x over previous
//
#include <hip/hip_runtime.h>

#define NPTS 16384
#define CDIM 64

using bf16x8 = __attribute__((ext_vector_type(8))) short;
using s16x4  = __attribute__((ext_vector_type(4))) short;
using f32x4  = __attribute__((ext_vector_type(4))) float;
using i32x4  = __attribute__((ext_vector_type(4))) int;

static __device__ __forceinline__ float b2f(short h){
  unsigned u = ((unsigned)(unsigned short)h) << 16;
  return __builtin_bit_cast(float, u);
}
static __device__ __forceinline__ short f2b(float f){
  unsigned u = __builtin_bit_cast(unsigned, f);
  u = (u + 0x7fffu + ((u >> 16) & 1u)) >> 16;
  return (short)u;
}

// ---- K1: x -> hi-bf16 plane + 0.5*||x||^2 ----
__global__ __launch_bounds__(256) void k_prep(const float* __restrict__ xf,
    short* __restrict__ xh, float* __restrict__ sq05){
  const int tid = threadIdx.x;
  const int row = blockIdx.x*64 + (tid >> 2);
  const int part = tid & 3;
  const float* p = xf + row*CDIM + part*16;
  float ps = 0.f;
  bf16x8 vh0, vh1;
  #pragma unroll
  for (int e = 0; e < 8; ++e){
    float f = p[e];
    vh0[e] = f2b(f);
    ps = fmaf(f, f, ps);
  }
  #pragma unroll
  for (int e = 0; e < 8; ++e){
    float f = p[8 + e];
    vh1[e] = f2b(f);
    ps = fmaf(f, f, ps);
  }
  *(bf16x8*)(xh + row*CDIM + part*16)     = vh0;
  *(bf16x8*)(xh + row*CDIM + part*16 + 8) = vh1;
  ps += __shfl_down(ps, 2);
  ps += __shfl_down(ps, 1);
  if (part == 0) sq05[row] = 0.5f * ps;
}

// ---- K2: W^T bf16, XOR-swizzled (layout k_mlp reads) ----
__global__ __launch_bounds__(256) void k_wprep(const float* __restrict__ Wf,
    short* __restrict__ WtG){
  const int n = threadIdx.x;
  const int kq = blockIdx.x;               // k = kq*4+e
  const int chunk = (kq >> 1) ^ (n & 15);
  s16x4 v;
  #pragma unroll
  for (int e = 0; e < 4; ++e) v[e] = f2b(Wf[(kq*4 + e)*256 + n]);
  *(s16x4*)(WtG + n*128 + chunk*8 + (kq & 1)*4) = v;
}

// ---- K3: hi-bf16 distance GEMM + streaming top-16 per j-quarter ----
// grid 1024 = (i-tile 0..255) x (j-quarter 0..3); 256 thr = 4 waves.
// Wave w owns i-rows rb..rb+15. 128-j double-buffered tiles; one barrier/t.
// Self-match (j==i) is allowed into the list; k_mlp ejects it (idx==i -> inf).
__global__ __launch_bounds__(256) void k_knn(const short* __restrict__ xh,
    const float* __restrict__ sq05, int* __restrict__ cand){
  __shared__ __align__(16) short Bh[2][128*72];
  __shared__ float sqt[2][128];
  const int tid = threadIdx.x, lane = tid & 63, w = tid >> 6;
  const int l15 = lane & 15, quad = lane >> 4;
  const int q = blockIdx.x & 3, ib = blockIdx.x >> 2;
  const int rb = ib*64 + w*16;
  const int jbase = q*4096;
  const int thrsrc = (lane & 48) | 15;

  bf16x8 ah[2];
  #pragma unroll
  for (int ks = 0; ks < 2; ++ks)
    ah[ks] = *(const bf16x8*)(xh + (rb + l15)*CDIM + ks*32 + quad*8);

  float lv[4]; int li[4]; float thr[4];
  #pragma unroll
  for (int r = 0; r < 4; ++r){
    lv[r] = __builtin_inff(); li[r] = 0; thr[r] = __builtin_inff();
  }

  // stage tile 0
  #pragma unroll
  for (int g = 0; g < 4; ++g){
    int c = g*256 + tid, row = c >> 3, seg = c & 7;
    *(bf16x8*)(&Bh[0][row*72 + seg*8]) =
        *(const bf16x8*)(xh + (jbase + row)*CDIM + seg*8);
  }
  if (tid < 128) sqt[0][tid] = sq05[jbase + tid];
  __syncthreads();

  #pragma unroll 1
  for (int t = 0; t < 32; ++t){
    const int cur = t & 1;
    const int j0 = jbase + t*128;
    if (t < 31){
      const int jn = j0 + 128;
      #pragma unroll
      for (int g = 0; g < 4; ++g){
        int c = g*256 + tid, row = c >> 3, seg = c & 7;
        *(bf16x8*)(&Bh[cur^1][row*72 + seg*8]) =
            *(const bf16x8*)(xh + (jn + row)*CDIM + seg*8);
      }
      if (tid < 128) sqt[cur^1][tid] = sq05[jn + tid];
    }

    f32x4 acc[8];
    #pragma unroll
    for (int js = 0; js < 8; ++js) acc[js] = (f32x4){0.f,0.f,0.f,0.f};
    #pragma unroll
    for (int ks = 0; ks < 2; ++ks){
      #pragma unroll
      for (int js = 0; js < 8; ++js){
        bf16x8 bh = *(const bf16x8*)(&Bh[cur][(js*16 + l15)*72 + (ks*4 + quad)*8]);
        acc[js] = __builtin_amdgcn_mfma_f32_16x16x32_bf16(ah[ks], bh, acc[js], 0,0,0);
      }
    }

    // rank by s = 0.5*sq[j] - dot (monotone in d)
    #pragma unroll
    for (int js = 0; js < 8; ++js){
      float sqv = sqt[cur][js*16 + l15];
      float s4[4];
      #pragma unroll
      for (int r = 0; r < 4; ++r) s4[r] = sqv - acc[js][r];
      #pragma unroll
      for (int r = 0; r < 4; ++r){
        unsigned long long bal = __ballot(s4[r] < thr[r]);
        unsigned qb = (unsigned)((bal >> (quad*16)) & 0xffffull);
        while (qb){
          int jj = __builtin_ctz(qb); qb &= qb - 1u;
          float cv = __shfl(s4[r], quad*16 + jj);
          int   cj = j0 + js*16 + jj;
          unsigned long long b2 = __ballot(lv[r] <= cv);
          int pos = __popc((unsigned)((b2 >> (quad*16)) & 0xffffull));
          float upv = __shfl_up(lv[r], 1, 16);
          int   upi = __shfl_up(li[r], 1, 16);
          if (l15 == pos){ lv[r] = cv; li[r] = cj; }
          else if (l15 > pos){ lv[r] = upv; li[r] = upi; }
          thr[r] = __shfl(lv[r], thrsrc);
        }
      }
    }
    __syncthreads();
  }

  #pragma unroll
  for (int r = 0; r < 4; ++r)
    cand[(rb + quad*4 + r)*64 + q*16 + l15] = li[r];
}

// ---- K4: exact fp32 rescore of 64 candidates + bitonic top-16 + MLP ----
// (byte-identical to round 11 — proven)
__global__ __launch_bounds__(256) void k_mlp(const float* __restrict__ xf,
    const short* __restrict__ WtG, const float* __restrict__ bfp,
    const int* __restrict__ cand, float* __restrict__ y){
  __shared__ __align__(16) short Wt[256*128];
  const int tid = threadIdx.x, lane = tid & 63, w = tid >> 6;
  const int l15 = lane & 15, quad = lane >> 4;
  for (int c = tid; c < 4096; c += 256)
    ((i32x4*)Wt)[c] = ((const i32x4*)WtG)[c];
  __syncthreads();
  const int ibase = blockIdx.x*32 + w*8;

  #pragma unroll 1
  for (int it = 0; it < 8; ++it){
    const int i = ibase + it;
    int idx = cand[i*64 + lane] & (NPTS - 1);

    float v;
    {
      const float* pi2 = xf + i*CDIM;
      const float* pj2 = xf + idx*CDIM;
      float qa[8], qb[8], qd[8];
      #pragma unroll
      for (int e = 0; e < 8; ++e){
        float a = pi2[e], b = pj2[e];
        qa[e] = a*a; qb[e] = b*b; qd[e] = a*b;
      }
      #pragma unroll
      for (int k2 = 1; k2 < 8; ++k2)
        #pragma unroll
        for (int e = 0; e < 8; ++e){
          float a = pi2[k2*8+e], b = pj2[k2*8+e];
          qa[e] += a*a; qb[e] += b*b; qd[e] += a*b;
        }
      float sa = ((qa[0]+qa[1])+(qa[2]+qa[3])) + ((qa[4]+qa[5])+(qa[6]+qa[7]));
      float sb = ((qb[0]+qb[1])+(qb[2]+qb[3])) + ((qb[4]+qb[5])+(qb[6]+qb[7]));
      float sd = ((qd[0]+qd[1])+(qd[2]+qd[3])) + ((qd[4]+qd[5])+(qd[6]+qd[7]));
      v = fmaf(-2.f, sd, sa + sb);
      if (idx == i) v = __builtin_inff();
    }

    #pragma unroll
    for (int k = 2; k <= 64; k <<= 1){
      #pragma unroll
      for (int j = k >> 1; j > 0; j >>= 1){
        float pv = __shfl_xor(v, j); int pi = __shfl_xor(idx, j);
        bool dir = ((lane & k) == 0);
        bool lower = ((lane & j) == 0);
        bool pless = (pv < v) || (pv == v && pi < idx);
        bool take = (lower == dir) ? pless : !pless;
        if (take){ v = pv; idx = pi; }
      }
    }
    int nb = __shfl(idx, l15) & (NPTS - 1);

    const float* xi = xf + i*CDIM;
    const float* xj = xf + nb*CDIM;
    bf16x8 afr[4];
    #pragma unroll
    for (int e = 0; e < 8; ++e){
      float a0 = xi[quad*8 + e];
      float a1 = xi[32 + quad*8 + e];
      float b0 = xj[quad*8 + e];
      float b1 = xj[32 + quad*8 + e];
      afr[0][e] = f2b(a0);
      afr[1][e] = f2b(a1);
      afr[2][e] = f2b(b0 - a0);
      afr[3][e] = f2b(b1 - a1);
    }
    f32x4 acc2[16];
    #pragma unroll
    for (int nt = 0; nt < 16; ++nt) acc2[nt] = (f32x4){0.f,0.f,0.f,0.f};
    #pragma unroll
    for (int ks = 0; ks < 4; ++ks){
      #pragma unroll
      for (int nt = 0; nt < 16; ++nt){
        int chunkS = ((ks*4 + quad) ^ l15);
        bf16x8 b = *(const bf16x8*)(Wt + (nt*16 + l15)*128 + chunkS*8);
        acc2[nt] = __builtin_amdgcn_mfma_f32_16x16x32_bf16(afr[ks], b, acc2[nt], 0, 0, 0);
      }
    }
    #pragma unroll
    for (int nt = 0; nt < 16; ++nt){
      float m = fmaxf(fmaxf(acc2[nt][0], acc2[nt][1]), fmaxf(acc2[nt][2], acc2[nt][3]));
      m = fmaxf(m, __shfl_xor(m, 16));
      m = fmaxf(m, __shfl_xor(m, 32));
      int col = nt*16 + l15;
      float o = fmaxf(m + bfp[col], 0.f);
      if (lane < 16)
        y[(i*4 + (col & 3))*CDIM + (col >> 2)] = o;
    }
  }
}

extern "C" void kernel_launch(void* const* d_in, const int* in_sizes, int n_in,
                              void* d_out, int out_size, void* d_ws, size_t ws_size,
                              hipStream_t stream){
  const float* x    = (const float*)d_in[0];
  const float* Wm   = (const float*)d_in[1];
  const float* bias = (const float*)d_in[2];
  float* y = (float*)d_out;
  char* ws = (char*)d_ws;
  short* xh   = (short*)ws;                              // 2 MB
  float* sq05 = (float*)(ws + (2 << 20));                // 64 KB
  short* WtG  = (short*)(ws + (2 << 20) + (64 << 10));   // 64 KB
  int*   cand = (int*)  (ws + (2 << 20) + (128 << 10));  // 4 MB
  (void)in_sizes; (void)n_in; (void)out_size; (void)ws_size;

  k_prep <<<256,  256, 0, stream>>>(x, xh, sq05);
  k_wprep<<<32,   256, 0, stream>>>(Wm, WtG);
  k_knn  <<<1024, 256, 0, stream>>>(xh, sq05, cand);
  k_mlp  <<<512,  256, 0, stream>>>(x, WtG, bias, cand, y);
}